// Round 6
// baseline (215.802 us; speedup 1.0000x reference)
//
#include <hip/hip_runtime.h>
#include <hip/hip_bf16.h>
#include <stdint.h>

// KAN layer: out[b,k] = sum_{i,j} B_j(x[b,i]) * W[k,i,j] + bias[k]
// batch=4096, in=512, out=512, num_basis=30 (padded 32), order=3
// GEMM: M=4096, N=512, K'=16384. Basis sparse (4 nonzeros/feature) stored as
// uint4 {N0N1,N2N3,j0,-} per (f,b). A-fragments built IN REGISTERS (128-bit
// funnel placement) -> no A LDS, 1 barrier/K-step, dbuf B via global_load_lds.

#define BATCH 4096
#define INF   512
#define OUTF  512
#define NB    30
#define NBP   32
#define NKNOT 34
#define KDIMP (INF * NBP)          // 16384

#define BM 128
#define BN 128
#define BK 64                      // 2 features per K-step
#define KSPLIT 8
#define KCHUNK (KDIMP / KSPLIT)    // 2048
#define NT     (KCHUNK / BK)       // 32
#define FPC    (KCHUNK / NBP)      // 64 features per chunk

typedef short v8s __attribute__((ext_vector_type(8)));
typedef float v4f __attribute__((ext_vector_type(4)));

__device__ __forceinline__ unsigned short f2bf(float f) {
  uint32_t u = __float_as_uint(f);
  uint32_t r = (u + 0x7fffu + ((u >> 16) & 1u)) >> 16;
  return (unsigned short)r;
}

__device__ __forceinline__ void gload16(const unsigned short* g, unsigned short* l) {
  auto gp = reinterpret_cast<const __attribute__((address_space(1))) unsigned short*>(
      reinterpret_cast<uintptr_t>(g));
  auto lp = reinterpret_cast<__attribute__((address_space(3))) unsigned short*>(
      reinterpret_cast<uintptr_t>(l));
  __builtin_amdgcn_global_load_lds(gp, lp, 16, 0, 0);
}

// Place the 4 packed bf16 (64-bit v) at short-offset d within an 8-short
// (128-bit) window. Branchless; d in [-24,27], nonzero overlap iff -3<d<8.
__device__ __forceinline__ v8s place4(uint64_t v, int d) {
  int s = d * 16;
  uint32_t ud = (uint32_t)d;
  uint64_t vls    = v << (s & 63);          // lo for d in [0,3]; hi for d in [4,7]
  uint64_t vrs_hi = v >> ((64 - s) & 63);   // hi for d in [1,3]
  uint64_t vrs_lo = v >> ((-s) & 63);       // lo for d in [-3,-1]
  uint64_t lo = (ud <= 3u) ? vls : (((uint32_t)(-d) - 1u) <= 2u ? vrs_lo : 0ull);
  uint64_t hi = ((ud - 1u) <= 2u) ? vrs_hi : (((ud - 4u) <= 3u) ? vls : 0ull);
  union { uint32_t u[4]; v8s s8; } r;
  r.u[0] = (uint32_t)lo; r.u[1] = (uint32_t)(lo >> 32);
  r.u[2] = (uint32_t)hi; r.u[3] = (uint32_t)(hi >> 32);
  return r.s8;
}

// ---------------- kernel 1: W fp32 -> bf16, pad 30 -> 32 cols ----------------
__global__ __launch_bounds__(256) void w_cast_kernel(const float* __restrict__ in,
                                                     unsigned short* __restrict__ out) {
  int idx = blockIdx.x * 256 + threadIdx.x;       // dword index
  int k   = idx >> 13;
  int rem = idx & 8191;
  int i   = rem >> 4;
  int jp  = rem & 15;
  int j   = jp * 2;
  const float* src = in + ((size_t)k * INF + i) * NB;
  float lo = (j     < NB) ? src[j]     : 0.f;
  float hi = (j + 1 < NB) ? src[j + 1] : 0.f;
  ((uint32_t*)out)[idx] = (uint32_t)f2bf(lo) | ((uint32_t)f2bf(hi) << 16);
}

// ---------------- kernel 2: sparse basis precompute --------------------------
// valsJ[f][b] = {N0|N1<<16, N2|N3<<16, j0, 0}; feature-major, coalesced.
__global__ __launch_bounds__(256) void basis_kernel(const float* __restrict__ x,
                                                    const float* __restrict__ knots,
                                                    uint4* __restrict__ valsJ) {
  __shared__ float tile[32][33];
  int b0 = blockIdx.x * 32;
  int f0 = blockIdx.y * 32;
  int lx = threadIdx.x & 31;
  int ly = threadIdx.x >> 5;                      // 0..7
  #pragma unroll
  for (int q = 0; q < 4; ++q)
    tile[ly + q * 8][lx] = x[(size_t)(b0 + ly + q * 8) * INF + f0 + lx]; // [b][f]
  __syncthreads();
  #pragma unroll
  for (int q = 0; q < 4; ++q) {
    int fy = ly + q * 8;
    float xv = tile[lx][fy];                      // b = b0+lx
    const float* tk = knots + (size_t)(f0 + fy) * NKNOT;
    uint4 pv = {0u, 0u, 0u, 0u};
    float tlo = tk[3], thi = tk[30];
    if (xv >= tlo && xv <= thi) {
      float t0v = tk[0];
      float h   = tk[1] - t0v;
      int m = (int)floorf((xv - t0v) * __builtin_amdgcn_rcpf(h));
      m = m < 3 ? 3 : (m > 30 ? 30 : m);
      while (m > 3 && xv < tk[m]) --m;
      while (m < 30 && xv >= tk[m + 1]) ++m;
      float Nv[4], left[4], right[4];
      Nv[0] = 1.f;
      #pragma unroll
      for (int d = 1; d <= 3; ++d) {
        left[d]  = xv - tk[m + 1 - d];
        right[d] = tk[m + d] - xv;
        float saved = 0.f;
        #pragma unroll
        for (int r = 0; r < d; ++r) {
          float temp = Nv[r] * __builtin_amdgcn_rcpf(right[r + 1] + left[d - r]);
          Nv[r] = saved + right[r + 1] * temp;
          saved = left[d - r] * temp;
        }
        Nv[d] = saved;
      }
      pv.x = (uint32_t)f2bf(Nv[0]) | ((uint32_t)f2bf(Nv[1]) << 16);
      pv.y = (uint32_t)f2bf(Nv[2]) | ((uint32_t)f2bf(Nv[3]) << 16);
      pv.z = (uint32_t)(m - 3);                   // j0 in 0..27
    }
    valsJ[(size_t)(f0 + fy) * BATCH + b0 + lx] = pv;
  }
}

// ---------------- kernel 3: bias init ----------------------------------------
__global__ __launch_bounds__(256) void bias_kernel(const float* __restrict__ bias,
                                                   float* __restrict__ out) {
  int idx = blockIdx.x * 256 + threadIdx.x;
  out[idx] = bias[idx & (OUTF - 1)];
}

// ---------------- kernel 4: fused GEMM (reg-A, dbuf-B, 1 barrier/iter) -------
__global__ __launch_bounds__(256, 3) void gemm_kernel(const uint4* __restrict__ valsJ,
                                                      const unsigned short* __restrict__ Bt,
                                                      float* __restrict__ C) {
  __shared__ unsigned short Bs[2][BN * BK];   // 2 x 16 KB
  int tid  = threadIdx.x;
  int lane = tid & 63;
  int w    = tid >> 6;

  // XCD-chunked bijective swizzle (1024 blocks, 128/XCD)
  int bid = blockIdx.x;
  int swz = (bid & 7) * 128 + (bid >> 3);
  int bn  = swz >> 8;
  int rem = swz & 255;
  int ks  = rem >> 5;
  int bm  = rem & 31;

  int row0 = bm * BM;
  int col0 = bn * BN;
  int kk0  = ks * KCHUNK;
  int fbase = ks * FPC;

  int wr  = (w >> 1) & 1;
  int wc  = w & 1;
  int r16 = lane & 15;
  int kg  = lane >> 4;

  // B staging (pre-swizzled global source, linear LDS dest)
  int lrow = lane >> 3;
  int lseg = (lane & 7) ^ lrow;
  const unsigned short* gb = Bt + (size_t)(col0 + w * 8 + lrow) * KDIMP + kk0 + lseg * 8;

  unsigned s0   = ((unsigned)kg ^ (unsigned)(r16 & 7)) << 4;
  unsigned boff = (unsigned)(wc * 64 + r16) * 128;

  // A source: lane covers rows row0 + wr*64 + r16 + mi*16, features fbase+2t+hf
  const uint4* vbase = valsJ + (size_t)fbase * BATCH + row0 + wr * 64 + r16;

  v4f acc[4][4];
  #pragma unroll
  for (int i = 0; i < 4; ++i)
    #pragma unroll
    for (int j = 0; j < 4; ++j)
      acc[i][j] = (v4f){0.f, 0.f, 0.f, 0.f};

  // prologue: prefetch A-side (t=0) and stage B (t=0)
  uint4 pf[8];
  #pragma unroll
  for (int mi = 0; mi < 4; ++mi)
    #pragma unroll
    for (int hfi = 0; hfi < 2; ++hfi)
      pf[mi * 2 + hfi] = vbase[(size_t)hfi * BATCH + mi * 16];
  #pragma unroll
  for (int q = 0; q < 4; ++q)
    gload16(gb + (size_t)q * (32 * KDIMP), &Bs[0][w * 512 + q * 2048]);
  __syncthreads();

  for (int t = 0; t < NT; ++t) {
    int c = t & 1;
    // construct A fragments in registers (pf dies here)
    v8s af[2][4];                        // [kc][mi]
    #pragma unroll
    for (int mi = 0; mi < 4; ++mi)
      #pragma unroll
      for (int kc = 0; kc < 2; ++kc) {
        uint4 p = pf[mi * 2 + kc];
        uint64_t v = (uint64_t)p.x | ((uint64_t)p.y << 32);
        af[kc][mi] = place4(v, (int)p.z - kg * 8);
      }
    // stage t+1: B into other buffer, A prefetch into pf
    if (t + 1 < NT) {
      const unsigned short* src = gb + (size_t)(t + 1) * BK;
      #pragma unroll
      for (int q = 0; q < 4; ++q)
        gload16(src + (size_t)q * (32 * KDIMP), &Bs[c ^ 1][w * 512 + q * 2048]);
      size_t fo = (size_t)(2 * (t + 1)) * BATCH;
      #pragma unroll
      for (int mi = 0; mi < 4; ++mi)
        #pragma unroll
        for (int hfi = 0; hfi < 2; ++hfi)
          pf[mi * 2 + hfi] = vbase[fo + (size_t)hfi * BATCH + mi * 16];
    }
    // compute on buffer c
    const char* Bb = (const char*)Bs[c];
    #pragma unroll
    for (int kc = 0; kc < 2; ++kc) {
      unsigned sk = s0 ^ (unsigned)(kc << 6);
      v8s bf[4];
      #pragma unroll
      for (int ni = 0; ni < 4; ++ni)
        bf[ni] = *(const v8s*)(Bb + boff + ni * 2048 + sk);
      #pragma unroll
      for (int mi = 0; mi < 4; ++mi)
        #pragma unroll
        for (int ni = 0; ni < 4; ++ni)
          acc[mi][ni] = __builtin_amdgcn_mfma_f32_16x16x32_bf16(af[kc][mi], bf[ni], acc[mi][ni], 0, 0, 0);
    }
    __syncthreads();                     // drains vmcnt: tile t+1 ready
  }

  // epilogue: C/D layout col=lane&15, row=(lane>>4)*4+reg  [m89/m91]
  int crow = (lane >> 4) * 4;
  int ccol = lane & 15;
  #pragma unroll
  for (int mi = 0; mi < 4; ++mi) {
    #pragma unroll
    for (int ni = 0; ni < 4; ++ni) {
      int r = row0 + wr * 64 + mi * 16 + crow;
      int c = col0 + wc * 64 + ni * 16 + ccol;
      #pragma unroll
      for (int q = 0; q < 4; ++q)
        atomicAdd(&C[(size_t)(r + q) * OUTF + c], acc[mi][ni][q]);
    }
  }
}

extern "C" void kernel_launch(void* const* d_in, const int* in_sizes, int n_in,
                              void* d_out, int out_size, void* d_ws, size_t ws_size,
                              hipStream_t stream) {
  const float* x     = (const float*)d_in[0];
  const float* knots = (const float*)d_in[1];
  const float* W     = (const float*)d_in[2];
  const float* bias  = (const float*)d_in[3];
  float* out = (float*)d_out;

  // ws: Wt bf16 [512][16384] (16 MB) | valsJ uint4 [512][4096] (33.5 MB)
  unsigned short* Wt    = (unsigned short*)d_ws;
  uint4*          valsJ = (uint4*)((char*)d_ws + (size_t)OUTF * KDIMP * 2);

  w_cast_kernel<<<(OUTF * KDIMP / 2) / 256, 256, 0, stream>>>(W, Wt);
  basis_kernel<<<dim3(BATCH / 32, INF / 32), 256, 0, stream>>>(x, knots, valsJ);
  bias_kernel<<<(BATCH * OUTF) / 256, 256, 0, stream>>>(bias, out);
  gemm_kernel<<<(BATCH / BM) * (OUTF / BN) * KSPLIT, 256, 0, stream>>>(valsJ, Wt, out);
}

// Round 7
// 206.400 us; speedup vs baseline: 1.0455x; 1.0455x over previous
//
#include <hip/hip_runtime.h>
#include <hip/hip_bf16.h>
#include <stdint.h>

// KAN layer: out[b,k] = sum_{i,j} B_j(x[b,i]) * W[k,i,j] + bias[k]
// batch=4096, in=512, out=512, num_basis=30 (padded 32), order=3
// GEMM: M=4096, N=512, K'=16384. Sparse basis (4 nnz) precomputed as uint4
// {N0N1,N2N3,j0,-}; expanded into swizzled LDS by writeA inside the GEMM.
// GEMM structure: 256x256 tile, 8 waves, BK=64, 4 phases/K-step with raw
// barriers + ONE counted drain per K-step (8-phase-style schedule, T3/T4/T5).

#define BATCH 4096
#define INF   512
#define OUTF  512
#define NB    30
#define NBP   32
#define NKNOT 34
#define KDIMP (INF * NBP)          // 16384

#define BM 256
#define BN 256
#define BK 64                      // 2 features per K-step
#define KSPLIT 8
#define KCHUNK (KDIMP / KSPLIT)    // 2048
#define NSTEPS (KCHUNK / BK)       // 32
#define FPC    (KCHUNK / NBP)      // 64 features per chunk

typedef short v8s __attribute__((ext_vector_type(8)));
typedef float v4f __attribute__((ext_vector_type(4)));

__device__ __forceinline__ unsigned short f2bf(float f) {
  uint32_t u = __float_as_uint(f);
  uint32_t r = (u + 0x7fffu + ((u >> 16) & 1u)) >> 16;
  return (unsigned short)r;
}

__device__ __forceinline__ void gload16(const unsigned short* g, unsigned short* l) {
  auto gp = reinterpret_cast<const __attribute__((address_space(1))) unsigned short*>(
      reinterpret_cast<uintptr_t>(g));
  auto lp = reinterpret_cast<__attribute__((address_space(3))) unsigned short*>(
      reinterpret_cast<uintptr_t>(l));
  __builtin_amdgcn_global_load_lds(gp, lp, 16, 0, 0);
}

// ---------------- kernel 1: W fp32 -> bf16, pad 30 -> 32 cols ----------------
__global__ __launch_bounds__(256) void w_cast_kernel(const float* __restrict__ in,
                                                     unsigned short* __restrict__ out) {
  int idx = blockIdx.x * 256 + threadIdx.x;       // dword index
  int k   = idx >> 13;
  int rem = idx & 8191;
  int i   = rem >> 4;
  int jp  = rem & 15;
  int j   = jp * 2;
  const float* src = in + ((size_t)k * INF + i) * NB;
  float lo = (j     < NB) ? src[j]     : 0.f;
  float hi = (j + 1 < NB) ? src[j + 1] : 0.f;
  ((uint32_t*)out)[idx] = (uint32_t)f2bf(lo) | ((uint32_t)f2bf(hi) << 16);
}

// ---------------- kernel 2: sparse basis precompute --------------------------
// valsJ[f][b] = {N0|N1<<16, N2|N3<<16, j0, 0}; feature-major, coalesced.
__global__ __launch_bounds__(256) void basis_kernel(const float* __restrict__ x,
                                                    const float* __restrict__ knots,
                                                    uint4* __restrict__ valsJ) {
  __shared__ float tile[32][33];
  int b0 = blockIdx.x * 32;
  int f0 = blockIdx.y * 32;
  int lx = threadIdx.x & 31;
  int ly = threadIdx.x >> 5;                      // 0..7
  #pragma unroll
  for (int q = 0; q < 4; ++q)
    tile[ly + q * 8][lx] = x[(size_t)(b0 + ly + q * 8) * INF + f0 + lx]; // [b][f]
  __syncthreads();
  #pragma unroll
  for (int q = 0; q < 4; ++q) {
    int fy = ly + q * 8;
    float xv = tile[lx][fy];                      // b = b0+lx
    const float* tk = knots + (size_t)(f0 + fy) * NKNOT;
    uint4 pv = {0u, 0u, 0u, 0u};
    float tlo = tk[3], thi = tk[30];
    if (xv >= tlo && xv <= thi) {
      float t0v = tk[0];
      float h   = tk[1] - t0v;
      int m = (int)floorf((xv - t0v) * __builtin_amdgcn_rcpf(h));
      m = m < 3 ? 3 : (m > 30 ? 30 : m);
      while (m > 3 && xv < tk[m]) --m;
      while (m < 30 && xv >= tk[m + 1]) ++m;
      float Nv[4], left[4], right[4];
      Nv[0] = 1.f;
      #pragma unroll
      for (int d = 1; d <= 3; ++d) {
        left[d]  = xv - tk[m + 1 - d];
        right[d] = tk[m + d] - xv;
        float saved = 0.f;
        #pragma unroll
        for (int r = 0; r < d; ++r) {
          float temp = Nv[r] * __builtin_amdgcn_rcpf(right[r + 1] + left[d - r]);
          Nv[r] = saved + right[r + 1] * temp;
          saved = left[d - r] * temp;
        }
        Nv[d] = saved;
      }
      pv.x = (uint32_t)f2bf(Nv[0]) | ((uint32_t)f2bf(Nv[1]) << 16);
      pv.y = (uint32_t)f2bf(Nv[2]) | ((uint32_t)f2bf(Nv[3]) << 16);
      pv.z = (uint32_t)(m - 3);                   // j0 in 0..27
    }
    valsJ[(size_t)(f0 + fy) * BATCH + b0 + lx] = pv;
  }
}

// ---------------- kernel 3: bias init ----------------------------------------
__global__ __launch_bounds__(256) void bias_kernel(const float* __restrict__ bias,
                                                   float* __restrict__ out) {
  int idx = blockIdx.x * 256 + threadIdx.x;
  out[idx] = bias[idx & (OUTF - 1)];
}

// ---------------- A expand: compact (v,j0) -> swizzled LDS -------------------
// Thread owns (row eb, feature-half hf): zero its 4 XOR-swizzled 16B slots,
// then overwrite the 2-3 dwords holding the 4 nonzeros. Race-free (disjoint
// slot sets per (eb,hf)).
__device__ __forceinline__ void writeA(unsigned short* Abuf, int eb, int hf, uint4 p) {
  unsigned rowb = (unsigned)eb * 128;
  unsigned x7   = (unsigned)(eb & 7);
  char* base = (char*)Abuf;
  uint4 z = {0u, 0u, 0u, 0u};
  #pragma unroll
  for (int s = 0; s < 4; ++s) {
    unsigned slot = ((unsigned)(hf * 4 + s)) ^ x7;
    *(uint4*)(base + rowb + (slot << 4)) = z;
  }
  int j0 = (int)p.z;
  int d0 = hf * 16 + (j0 >> 1);
  #define WR32(d, val) { unsigned by = (unsigned)(d) * 4u; \
    *(uint32_t*)(base + rowb + ((((by >> 4) ^ x7) << 4) | (by & 15u))) = (val); }
  if (j0 & 1) {
    WR32(d0,     p.x << 16);
    WR32(d0 + 1, (p.x >> 16) | (p.y << 16));
    WR32(d0 + 2, p.y >> 16);
  } else {
    WR32(d0,     p.x);
    WR32(d0 + 1, p.y);
  }
  #undef WR32
}

// ---------------- kernel 4: fused GEMM, 4-phase counted schedule -------------
__global__ __launch_bounds__(512, 2) void gemm_kernel(const uint4* __restrict__ valsJ,
                                                      const unsigned short* __restrict__ Bt,
                                                      float* __restrict__ C) {
  __shared__ unsigned short As[2][BM * BK];   // 2 x 32 KB
  __shared__ unsigned short Bs[2][BN * BK];   // 2 x 32 KB  (rows = W cols)
  int tid  = threadIdx.x;
  int lane = tid & 63;
  int w    = tid >> 6;                        // 0..7

  // XCD-chunked bijective swizzle (256 blocks, 32/XCD); ks inner-ish so an
  // XCD's 32 blocks share a 2 MB W window in L2.
  int bid = blockIdx.x;
  int swz = (bid & 7) * 32 + (bid >> 3);
  int bn  = swz >> 7;                         // 0..1
  int ks  = (swz >> 4) & 7;                   // 0..7
  int bm  = swz & 15;                         // 0..15

  int row0 = bm * BM;
  int col0 = bn * BN;
  int kk0  = ks * KCHUNK;
  int fbase = ks * FPC;

  int wr  = w >> 2;                           // 0..1 (M half)
  int wc  = w & 3;                            // 0..3 (N quarter)
  int r16 = lane & 15;
  int kg  = lane >> 4;

  // A expand mapping: thread -> (row eb, feature-half hf)
  int eb = tid & 255;
  int hf = tid >> 8;
  const uint4* vb = valsJ + ((size_t)(fbase + hf) * BATCH + row0 + eb);

  // B staging source (pre-swizzled global addr, linear LDS dest)
  int lrow = lane >> 3;                       // 0..7
  int lseg = (lane & 7) ^ lrow;
  const unsigned short* gb = Bt + (size_t)(col0 + w * 8 + lrow) * KDIMP + lseg * 8;

  unsigned s0   = ((unsigned)kg ^ (unsigned)(r16 & 7)) << 4;
  unsigned aoff = (unsigned)(wr * 128 + r16) * 128;   // +mi*16*128 per frag
  unsigned boff = (unsigned)(wc * 64 + r16) * 128;    // +ni*16*128 per frag

  v4f acc[8][4];
  #pragma unroll
  for (int i = 0; i < 8; ++i)
    #pragma unroll
    for (int j = 0; j < 4; ++j)
      acc[i][j] = (v4f){0.f, 0.f, 0.f, 0.f};

  // ---- prologue: stage step 0 fully; preload valsJ for step 1
  {
    uint4 vc = vb[0];
    writeA(&As[0][0], eb, hf, vc);
    const unsigned short* g0 = gb + kk0;
    #pragma unroll
    for (int pr = 0; pr < 4; ++pr)
      gload16(g0 + (size_t)pr * 64 * KDIMP, &Bs[0][pr * 4096 + w * 512]);
  }
  uint4 vn = vb[(size_t)2 * BATCH];           // step 1
  __syncthreads();                            // full drain once

  for (int t = 0; t < NSTEPS; ++t) {
    int p = t & 1;
    bool stage = (t + 1 < NSTEPS);
    unsigned short* An = &As[p ^ 1][0];
    unsigned short* Bn = &Bs[p ^ 1][0];
    const unsigned short* gsrc = gb + (size_t)(kk0 + (t + 1) * BK);
    if (stage) writeA(An, eb, hf, vn);        // LDS-only; covered by group-end lgkm+barrier

    const char* Ab = (const char*)&As[p][0];
    const char* Bb = (const char*)&Bs[p][0];
    v8s bf[2][4];
    uint4 vn2;
    #pragma unroll
    for (int mq = 0; mq < 4; ++mq) {
      if (mq == 0) {
        #pragma unroll
        for (int kc = 0; kc < 2; ++kc)
          #pragma unroll
          for (int ni = 0; ni < 4; ++ni)
            bf[kc][ni] = *(const v8s*)(Bb + boff + ni * 2048 + (s0 ^ (kc << 6)));
      }
      v8s af[2][2];
      #pragma unroll
      for (int q = 0; q < 2; ++q)
        #pragma unroll
        for (int kc = 0; kc < 2; ++kc)
          af[q][kc] = *(const v8s*)(Ab + aoff + (mq * 2 + q) * 2048 + (s0 ^ (kc << 6)));
      if (stage) {                            // issue B gloads early (phases 0-2)
        if (mq == 0) {
          gload16(gsrc,                        Bn + w * 512);
          gload16(gsrc + (size_t) 64 * KDIMP,  Bn +  4096 + w * 512);
        } else if (mq == 1) {
          gload16(gsrc + (size_t)128 * KDIMP,  Bn +  8192 + w * 512);
        } else if (mq == 2) {
          gload16(gsrc + (size_t)192 * KDIMP,  Bn + 12288 + w * 512);
        }
      }
      if (mq == 1) {
        int s2 = (t + 2 < NSTEPS) ? (t + 2) : (NSTEPS - 1);
        vn2 = vb[(size_t)2 * s2 * BATCH];     // valsJ prefetch (step t+2)
      }
      __builtin_amdgcn_s_barrier();
      __builtin_amdgcn_s_setprio(1);
      #pragma unroll
      for (int q = 0; q < 2; ++q)
        #pragma unroll
        for (int kc = 0; kc < 2; ++kc)
          #pragma unroll
          for (int ni = 0; ni < 4; ++ni)
            acc[mq * 2 + q][ni] = __builtin_amdgcn_mfma_f32_16x16x32_bf16(
                af[q][kc], bf[kc][ni], acc[mq * 2 + q][ni], 0, 0, 0);
      __builtin_amdgcn_s_setprio(0);
      if (mq < 3) __builtin_amdgcn_s_barrier();
    }
    // group end: ONE counted drain (B(t+1) DMA + writeA visibility), then barrier
    asm volatile("s_waitcnt vmcnt(0) lgkmcnt(0)" ::: "memory");
    __builtin_amdgcn_s_barrier();
    vn = vn2;
  }

  // epilogue: C/D layout col=lane&15, row=(lane>>4)*4+reg  [m89/m91]
  int crow = (lane >> 4) * 4;
  int ccol = lane & 15;
  #pragma unroll
  for (int mi = 0; mi < 8; ++mi) {
    #pragma unroll
    for (int ni = 0; ni < 4; ++ni) {
      int r = row0 + wr * 128 + mi * 16 + crow;
      int c = col0 + wc * 64 + ni * 16 + ccol;
      #pragma unroll
      for (int q = 0; q < 4; ++q)
        atomicAdd(&C[(size_t)(r + q) * OUTF + c], acc[mi][ni][q]);
    }
  }
}

extern "C" void kernel_launch(void* const* d_in, const int* in_sizes, int n_in,
                              void* d_out, int out_size, void* d_ws, size_t ws_size,
                              hipStream_t stream) {
  const float* x     = (const float*)d_in[0];
  const float* knots = (const float*)d_in[1];
  const float* W     = (const float*)d_in[2];
  const float* bias  = (const float*)d_in[3];
  float* out = (float*)d_out;

  // ws: Wt bf16 [512][16384] (16 MB) | valsJ uint4 [512][4096] (33.5 MB)
  unsigned short* Wt    = (unsigned short*)d_ws;
  uint4*          valsJ = (uint4*)((char*)d_ws + (size_t)OUTF * KDIMP * 2);

  w_cast_kernel<<<(OUTF * KDIMP / 2) / 256, 256, 0, stream>>>(W, Wt);
  basis_kernel<<<dim3(BATCH / 32, INF / 32), 256, 0, stream>>>(x, knots, valsJ);
  bias_kernel<<<(BATCH * OUTF) / 256, 256, 0, stream>>>(bias, out);
  gemm_kernel<<<(BATCH / BM) * (OUTF / BN) * KSPLIT, 512, 0, stream>>>(valsJ, Wt, out);
}

// Round 8
// 189.034 us; speedup vs baseline: 1.1416x; 1.0919x over previous
//
#include <hip/hip_runtime.h>
#include <hip/hip_bf16.h>
#include <stdint.h>

// KAN layer: out[b,k] = sum_{i,j} B_j(x[b,i]) * W[k,i,j] + bias[k]
// batch=4096, in=512, out=512, num_basis=30 (padded 32), order=3
// GEMM: M=4096, N=512, K'=16384. Sparse basis (4 nnz/feature) precomputed as
// uint4 {N0N1,N2N3,j0,-}; expanded into XOR-swizzled LDS by writeA in-GEMM.
// GEMM: 128x128 tile, 4 waves, BK=64, KSPLIT=4. B double-buffered with
// ISSUE-EARLY/DRAIN-LATE global_load_lds (DMA hidden under MFMA); A single
// buffer refreshed behind a mid-barrier. 3 blocks/CU.

#define BATCH 4096
#define INF   512
#define OUTF  512
#define NB    30
#define NBP   32
#define NKNOT 34
#define KDIMP (INF * NBP)          // 16384

#define BM 128
#define BN 128
#define BK 64                      // 2 features per K-step
#define KSPLIT 4
#define KCHUNK (KDIMP / KSPLIT)    // 4096
#define NT     (KCHUNK / BK)       // 64
#define FPC    (KCHUNK / NBP)      // 128 features per chunk

typedef short v8s __attribute__((ext_vector_type(8)));
typedef float v4f __attribute__((ext_vector_type(4)));

__device__ __forceinline__ unsigned short f2bf(float f) {
  uint32_t u = __float_as_uint(f);
  uint32_t r = (u + 0x7fffu + ((u >> 16) & 1u)) >> 16;
  return (unsigned short)r;
}

__device__ __forceinline__ void gload16(const unsigned short* g, unsigned short* l) {
  auto gp = reinterpret_cast<const __attribute__((address_space(1))) unsigned short*>(
      reinterpret_cast<uintptr_t>(g));
  auto lp = reinterpret_cast<__attribute__((address_space(3))) unsigned short*>(
      reinterpret_cast<uintptr_t>(l));
  __builtin_amdgcn_global_load_lds(gp, lp, 16, 0, 0);
}

// ---------------- kernel 1: W fp32 -> bf16, pad 30 -> 32 cols ----------------
__global__ __launch_bounds__(256) void w_cast_kernel(const float* __restrict__ in,
                                                     unsigned short* __restrict__ out) {
  int idx = blockIdx.x * 256 + threadIdx.x;       // dword index
  int k   = idx >> 13;
  int rem = idx & 8191;
  int i   = rem >> 4;
  int jp  = rem & 15;
  int j   = jp * 2;
  const float* src = in + ((size_t)k * INF + i) * NB;
  float lo = (j     < NB) ? src[j]     : 0.f;
  float hi = (j + 1 < NB) ? src[j + 1] : 0.f;
  ((uint32_t*)out)[idx] = (uint32_t)f2bf(lo) | ((uint32_t)f2bf(hi) << 16);
}

// ---------------- kernel 2: sparse basis precompute --------------------------
// valsJ[f][b] = {N0|N1<<16, N2|N3<<16, j0, 0}; feature-major, coalesced.
__global__ __launch_bounds__(256) void basis_kernel(const float* __restrict__ x,
                                                    const float* __restrict__ knots,
                                                    uint4* __restrict__ valsJ) {
  __shared__ float tile[32][33];
  int b0 = blockIdx.x * 32;
  int f0 = blockIdx.y * 32;
  int lx = threadIdx.x & 31;
  int ly = threadIdx.x >> 5;                      // 0..7
  #pragma unroll
  for (int q = 0; q < 4; ++q)
    tile[ly + q * 8][lx] = x[(size_t)(b0 + ly + q * 8) * INF + f0 + lx]; // [b][f]
  __syncthreads();
  #pragma unroll
  for (int q = 0; q < 4; ++q) {
    int fy = ly + q * 8;
    float xv = tile[lx][fy];                      // b = b0+lx
    const float* tk = knots + (size_t)(f0 + fy) * NKNOT;
    uint4 pv = {0u, 0u, 0u, 0u};
    float tlo = tk[3], thi = tk[30];
    if (xv >= tlo && xv <= thi) {
      float t0v = tk[0];
      float h   = tk[1] - t0v;
      int m = (int)floorf((xv - t0v) * __builtin_amdgcn_rcpf(h));
      m = m < 3 ? 3 : (m > 30 ? 30 : m);
      while (m > 3 && xv < tk[m]) --m;
      while (m < 30 && xv >= tk[m + 1]) ++m;
      float Nv[4], left[4], right[4];
      Nv[0] = 1.f;
      #pragma unroll
      for (int d = 1; d <= 3; ++d) {
        left[d]  = xv - tk[m + 1 - d];
        right[d] = tk[m + d] - xv;
        float saved = 0.f;
        #pragma unroll
        for (int r = 0; r < d; ++r) {
          float temp = Nv[r] * __builtin_amdgcn_rcpf(right[r + 1] + left[d - r]);
          Nv[r] = saved + right[r + 1] * temp;
          saved = left[d - r] * temp;
        }
        Nv[d] = saved;
      }
      pv.x = (uint32_t)f2bf(Nv[0]) | ((uint32_t)f2bf(Nv[1]) << 16);
      pv.y = (uint32_t)f2bf(Nv[2]) | ((uint32_t)f2bf(Nv[3]) << 16);
      pv.z = (uint32_t)(m - 3);                   // j0 in 0..27
    }
    valsJ[(size_t)(f0 + fy) * BATCH + b0 + lx] = pv;
  }
}

// ---------------- kernel 3: bias init ----------------------------------------
__global__ __launch_bounds__(256) void bias_kernel(const float* __restrict__ bias,
                                                   float* __restrict__ out) {
  int idx = blockIdx.x * 256 + threadIdx.x;
  out[idx] = bias[idx & (OUTF - 1)];
}

// ---------------- A expand: compact (v,j0) -> swizzled LDS -------------------
// Thread owns (row eb, feature-half hf): zero its 4 XOR-swizzled 16B slots,
// then overwrite the 2-3 dwords holding the 4 nonzeros. Slot sets disjoint
// across (eb,hf) -> race-free.
__device__ __forceinline__ void writeA(unsigned short* Abuf, int eb, int hf, uint4 p) {
  unsigned rowb = (unsigned)eb * 128;
  unsigned x7   = (unsigned)(eb & 7);
  char* base = (char*)Abuf;
  uint4 z = {0u, 0u, 0u, 0u};
  #pragma unroll
  for (int s = 0; s < 4; ++s) {
    unsigned slot = ((unsigned)(hf * 4 + s)) ^ x7;
    *(uint4*)(base + rowb + (slot << 4)) = z;
  }
  int j0 = (int)p.z;
  int d0 = hf * 16 + (j0 >> 1);
  #define WR32(d, val) { unsigned by = (unsigned)(d) * 4u; \
    *(uint32_t*)(base + rowb + ((((by >> 4) ^ x7) << 4) | (by & 15u))) = (val); }
  if (j0 & 1) {
    WR32(d0,     p.x << 16);
    WR32(d0 + 1, (p.x >> 16) | (p.y << 16));
    WR32(d0 + 2, p.y >> 16);
  } else {
    WR32(d0,     p.x);
    WR32(d0 + 1, p.y);
  }
  #undef WR32
}

// ---------------- kernel 4: fused GEMM (issue-early dbuf-B, single-A) --------
__global__ __launch_bounds__(256, 3) void gemm_kernel(const uint4* __restrict__ valsJ,
                                                      const unsigned short* __restrict__ Bt,
                                                      float* __restrict__ C) {
  __shared__ unsigned short As[BM * BK];       // 16 KB (single buffer)
  __shared__ unsigned short Bs[2][BN * BK];    // 2 x 16 KB
  int tid  = threadIdx.x;
  int lane = tid & 63;
  int w    = tid >> 6;

  // XCD-chunked bijective swizzle (512 blocks, 64/XCD); one bn per XCD,
  // 2 ks values -> 2 MB W window in L2 per XCD.
  int bid = blockIdx.x;
  int swz = (bid & 7) * 64 + (bid >> 3);
  int bn  = swz >> 7;                          // 0..3
  int rem = swz & 127;
  int ks  = rem >> 5;                          // 0..3
  int bm  = rem & 31;                          // 0..31

  int row0 = bm * BM;
  int col0 = bn * BN;
  int kk0  = ks * KCHUNK;
  int fbase = ks * FPC;

  int wr  = (w >> 1) & 1;
  int wc  = w & 1;
  int r16 = lane & 15;
  int kg  = lane >> 4;

  // A expand mapping
  int eb = tid & 127;
  int hf = tid >> 7;
  const uint4* vb = valsJ + ((size_t)(fbase + hf) * BATCH + row0 + eb);

  // B staging (pre-swizzled global source, linear LDS dest)
  int lrow = lane >> 3;
  int lseg = (lane & 7) ^ lrow;
  const unsigned short* gb = Bt + (size_t)(col0 + w * 8 + lrow) * KDIMP + kk0 + lseg * 8;

  unsigned s0   = ((unsigned)kg ^ (unsigned)(r16 & 7)) << 4;
  unsigned aoff = (unsigned)(wr * 64 + r16) * 128;
  unsigned boff = (unsigned)(wc * 64 + r16) * 128;

  v4f acc[4][4];
  #pragma unroll
  for (int i = 0; i < 4; ++i)
    #pragma unroll
    for (int j = 0; j < 4; ++j)
      acc[i][j] = (v4f){0.f, 0.f, 0.f, 0.f};

  // ---- prologue: stage step 0; preload valsJ for step 1
  {
    uint4 vc = vb[0];
    writeA(As, eb, hf, vc);
    #pragma unroll
    for (int q = 0; q < 4; ++q)
      gload16(gb + (size_t)q * (32 * KDIMP), &Bs[0][w * 512 + q * 2048]);
  }
  uint4 vn = vb[2 * BATCH];
  asm volatile("s_waitcnt vmcnt(0) lgkmcnt(0)" ::: "memory");
  __builtin_amdgcn_s_barrier();

  for (int t = 0; t < NT; ++t) {
    int c = t & 1;
    // issue B(t+1) DMA FIRST: in flight under the whole compute cluster
    if (t + 1 < NT) {
      const unsigned short* src = gb + (size_t)(t + 1) * BK;
      #pragma unroll
      for (int q = 0; q < 4; ++q)
        gload16(src + (size_t)q * (32 * KDIMP), &Bs[c ^ 1][w * 512 + q * 2048]);
    }
    uint4 vn2 = vn;
    if (t + 2 < NT) vn2 = vb[(size_t)(2 * (t + 2)) * BATCH];

    const char* Ab = (const char*)As;
    const char* Bb = (const char*)Bs[c];
    __builtin_amdgcn_s_setprio(1);
    #pragma unroll
    for (int kc = 0; kc < 2; ++kc) {
      unsigned sk = s0 ^ (unsigned)(kc << 6);
      v8s af[4], bf[4];
      #pragma unroll
      for (int mi = 0; mi < 4; ++mi)
        af[mi] = *(const v8s*)(Ab + aoff + mi * 2048 + sk);
      #pragma unroll
      for (int ni = 0; ni < 4; ++ni)
        bf[ni] = *(const v8s*)(Bb + boff + ni * 2048 + sk);
      #pragma unroll
      for (int mi = 0; mi < 4; ++mi)
        #pragma unroll
        for (int ni = 0; ni < 4; ++ni)
          acc[mi][ni] = __builtin_amdgcn_mfma_f32_16x16x32_bf16(af[mi], bf[ni], acc[mi][ni], 0, 0, 0);
    }
    __builtin_amdgcn_s_setprio(0);
    // all A-reads of step t consumed (compiler operand-waits) -> safe to refresh A
    __builtin_amdgcn_s_barrier();
    if (t + 1 < NT) writeA(As, eb, hf, vn);
    // drain: B(t+1) DMA (covered by compute above) + writeA visibility
    asm volatile("s_waitcnt vmcnt(0) lgkmcnt(0)" ::: "memory");
    __builtin_amdgcn_s_barrier();
    vn = vn2;
  }

  // epilogue: C/D layout col=lane&15, row=(lane>>4)*4+reg  [m89/m91]
  int crow = (lane >> 4) * 4;
  int ccol = lane & 15;
  #pragma unroll
  for (int mi = 0; mi < 4; ++mi) {
    #pragma unroll
    for (int ni = 0; ni < 4; ++ni) {
      int r = row0 + wr * 64 + mi * 16 + crow;
      int c = col0 + wc * 64 + ni * 16 + ccol;
      #pragma unroll
      for (int q = 0; q < 4; ++q)
        atomicAdd(&C[(size_t)(r + q) * OUTF + c], acc[mi][ni][q]);
    }
  }
}

extern "C" void kernel_launch(void* const* d_in, const int* in_sizes, int n_in,
                              void* d_out, int out_size, void* d_ws, size_t ws_size,
                              hipStream_t stream) {
  const float* x     = (const float*)d_in[0];
  const float* knots = (const float*)d_in[1];
  const float* W     = (const float*)d_in[2];
  const float* bias  = (const float*)d_in[3];
  float* out = (float*)d_out;

  // ws: Wt bf16 [512][16384] (16 MB) | valsJ uint4 [512][4096] (33.5 MB)
  unsigned short* Wt    = (unsigned short*)d_ws;
  uint4*          valsJ = (uint4*)((char*)d_ws + (size_t)OUTF * KDIMP * 2);

  w_cast_kernel<<<(OUTF * KDIMP / 2) / 256, 256, 0, stream>>>(W, Wt);
  basis_kernel<<<dim3(BATCH / 32, INF / 32), 256, 0, stream>>>(x, knots, valsJ);
  bias_kernel<<<(BATCH * OUTF) / 256, 256, 0, stream>>>(bias, out);
  gemm_kernel<<<(BATCH / BM) * (OUTF / BN) * KSPLIT, 256, 0, stream>>>(valsJ, Wt, out);
}